// Round 1
// baseline (389.037 us; speedup 1.0000x reference)
//
#include <hip/hip_runtime.h>

// BilinearResNet fused forward, round 5.
// Round 4 post-mortem: dur 130us/dispatch but VALUBusy only 30%, HBM 11%,
// conflicts 0 -> latency/sync-bound, not a roofline. Cause: __syncthreads per
// chunk emits s_waitcnt vmcnt(0) before s_barrier, draining the prefetch
// issued only ~500 cycles earlier (HBM latency ~900cy) -> ~450-cycle
// whole-block stall x 12 chunks. The double buffer was defeated by the drain.
// Fix (guide T3+T4): 3-deep pipeline, raw s_barrier + COUNTED vmcnt.
// Steady state keeps chunks c+1,c+2,c+3 in flight (12 vmem instrs/wave) and
// waits vmcnt(8) -> only the oldest chunk must have landed. Per-wave counted
// wait + barrier is collectively sufficient for cross-wave LDS visibility
// (m201-verified pattern). buf[c%3] is rewritten only after a barrier proving
// all waves finished reading chunk c.
// Compute/swizzle/tail/reduce/epilogue identical to round 4 (measured
// 0-conflict). LDS 48KB -> 3 blocks/CU (12 waves/CU); pipeline no longer
// needs cross-block overlap to hide latency.

#define IN_DIM   784
#define D_MODEL  16
#define HIDDEN   6
#define N_BLOCKS 4
#define N_CLS    10
#define BATCH    65536
#define NCHUNK   12        // 12 x 64-float chunks + 16-float tail

typedef const __attribute__((address_space(1))) void gvoid_t;
typedef __attribute__((address_space(3))) void svoid_t;

__global__ __launch_bounds__(256, 3) void bilinear_resnet_fused(
    const float* __restrict__ x,
    const float* __restrict__ W_embed,   // [16][784]
    const float* __restrict__ L_w,       // [4][6][16]
    const float* __restrict__ R_w,       // [4][6][16]
    const float* __restrict__ D_w,       // [4][16][6]
    const float* __restrict__ W_head,    // [10][16]
    float* __restrict__ out)
{
    __shared__ float4 buf[3][64 * 16];   // 3 x 16 KB, rotating

    const int tid  = threadIdx.x;
    const int lane = tid & 63;
    const int wv   = __builtin_amdgcn_readfirstlane(tid >> 6);  // 0..3 uniform
    const int row  = blockIdx.x * 64 + lane;
    const float* xtile = x + (size_t)blockIdx.x * 64 * IN_DIM;

    // staging decode (chunk-invariant): for (it, wv), lane l covers LDS slot
    // s = it*256 + wv*64 + l  ->  r = it*16 + wv*4 + (l>>4),
    // stored kk = (l&15) ^ (r&15).
    const int sub   = lane >> 4;
    const int rmod  = wv * 4 + sub;          // r & 15
    const int kk_l  = (lane & 15) ^ rmod;    // source column group (x4 floats)

    float acc[D_MODEL];
#pragma unroll
    for (int d = 0; d < D_MODEL; ++d) acc[d] = 0.f;

    // issue one chunk's staging (4 x global_load_lds width=16 per thread)
    auto stage = [&](int k, int slot) {
#pragma unroll
        for (int it = 0; it < 4; ++it) {
            const int r = it * 16 + rmod;
            const float* g = xtile + (size_t)r * IN_DIM + k * 64 + kk_l * 4;
            char* l = (char*)(&buf[slot][0]) + (it * 256 + wv * 64) * 16;
            __builtin_amdgcn_global_load_lds((gvoid_t*)g, (svoid_t*)l, 16, 0, 0);
        }
    };

    // compute one chunk: lane = row, wave handles kk = wv*4 + [0..4)
    auto compute = [&](int c, int slot) {
        const float* wc = W_embed + c * 64 + wv * 16;   // wave-uniform -> s_load
        const float4* bsrc = buf[slot];
#pragma unroll
        for (int j = 0; j < 4; ++j) {
            const int kk = wv * 4 + j;
            const float4 xv = bsrc[lane * 16 + (kk ^ (lane & 15))];
#pragma unroll
            for (int d = 0; d < D_MODEL; ++d) {
                const float* wd = wc + d * IN_DIM + j * 4;  // uniform
                float s = acc[d];
                s = fmaf(xv.x, wd[0], s);
                s = fmaf(xv.y, wd[1], s);
                s = fmaf(xv.z, wd[2], s);
                s = fmaf(xv.w, wd[3], s);
                acc[d] = s;
            }
        }
    };

    // ---- prologue: fill the 3-deep pipe (12 vmem instrs outstanding) ----
    stage(0, 0);
    stage(1, 1);
    stage(2, 2);
    asm volatile("s_waitcnt vmcnt(8)" ::: "memory");   // chunk 0 landed
    __builtin_amdgcn_s_barrier();                      // ...for every wave
    asm volatile("" ::: "memory");

    // ---- steady state: c = 0..8 ----
#pragma unroll 3
    for (int c = 0; c < NCHUNK - 3; ++c) {
        compute(c, c % 3);
        // own ds_reads of buf[c%3] complete (cheap: FMAs already consumed them)
        asm volatile("s_waitcnt lgkmcnt(0)" ::: "memory");
        __builtin_amdgcn_s_barrier();                  // all waves done reading buf[c%3]
        asm volatile("" ::: "memory");
        stage(c + 3, c % 3);                           // refill freed buffer
        // outstanding: chunks c+1,c+2,c+3 = 12 instrs; need c+1 done -> 8 left
        asm volatile("s_waitcnt vmcnt(8)" ::: "memory");
        __builtin_amdgcn_s_barrier();                  // chunk c+1 visible to all
        asm volatile("" ::: "memory");
    }

    // ---- drain: c = 9, 10, 11 (no more staging) ----
    compute(9, 0);
    asm volatile("s_waitcnt vmcnt(4)" ::: "memory");   // chunk 10 landed (11 in flight)
    __builtin_amdgcn_s_barrier();
    asm volatile("" ::: "memory");

    compute(10, 1);
    asm volatile("s_waitcnt vmcnt(0)" ::: "memory");   // chunk 11 landed
    __builtin_amdgcn_s_barrier();
    asm volatile("" ::: "memory");

    compute(11, 2);

    // ---- tail: columns 768..784 (one 64B line per row), direct global ----
    {
        const float4 xv = *reinterpret_cast<const float4*>(
            x + (size_t)row * IN_DIM + 768 + wv * 4);
        const float* wt = W_embed + 768 + wv * 4;   // uniform
#pragma unroll
        for (int d = 0; d < D_MODEL; ++d) {
            const float* wd = wt + d * IN_DIM;
            float s = acc[d];
            s = fmaf(xv.x, wd[0], s);
            s = fmaf(xv.y, wd[1], s);
            s = fmaf(xv.z, wd[2], s);
            s = fmaf(xv.w, wd[3], s);
            acc[d] = s;
        }
    }

    // ---- reduce 4 wave-partials per row (reuse buf[0], stride 17) ----
    // Safe: every wave past the c=10 barrier has finished chunk 9 (last buf[0]
    // reader), and partial reads happen after the __syncthreads below.
    float* parts = reinterpret_cast<float*>(&buf[0][0]);
    if (wv != 0) {
#pragma unroll
        for (int d = 0; d < D_MODEL; ++d)
            parts[((wv - 1) * 64 + lane) * 17 + d] = acc[d];
    }
    __syncthreads();
    if (wv != 0) return;

#pragma unroll
    for (int d = 0; d < D_MODEL; ++d)
        acc[d] += parts[(0 * 64 + lane) * 17 + d]
                + parts[(1 * 64 + lane) * 17 + d]
                + parts[(2 * 64 + lane) * 17 + d];

    // ---- bilinear residual blocks (wave 0; uniform weights -> scalar) ----
#pragma unroll
    for (int b = 0; b < N_BLOCKS; ++b) {
        const float* Lb = L_w + b * HIDDEN * D_MODEL;
        const float* Rb = R_w + b * HIDDEN * D_MODEL;
        const float* Db = D_w + b * D_MODEL * HIDDEN;
        float h[HIDDEN];
#pragma unroll
        for (int j = 0; j < HIDDEN; ++j) {
            float u = 0.f, v = 0.f;
#pragma unroll
            for (int d = 0; d < D_MODEL; ++d) {
                u = fmaf(acc[d], Lb[j * D_MODEL + d], u);
                v = fmaf(acc[d], Rb[j * D_MODEL + d], v);
            }
            h[j] = u * v;
        }
#pragma unroll
        for (int d = 0; d < D_MODEL; ++d) {
            float s = acc[d];
#pragma unroll
            for (int j = 0; j < HIDDEN; ++j) s = fmaf(h[j], Db[d * HIDDEN + j], s);
            acc[d] = s;
        }
        float* hout = out + (size_t)N_CLS * BATCH + (size_t)b * HIDDEN * BATCH
                      + (size_t)row * HIDDEN;
#pragma unroll
        for (int j = 0; j < HIDDEN; ++j) hout[j] = h[j];
    }

    // ---- head ----
    float* lout = out + (size_t)row * N_CLS;
#pragma unroll
    for (int k = 0; k < N_CLS; ++k) {
        float s = 0.f;
#pragma unroll
        for (int d = 0; d < D_MODEL; ++d) s = fmaf(acc[d], W_head[k * D_MODEL + d], s);
        lout[k] = s;
    }
}

extern "C" void kernel_launch(void* const* d_in, const int* in_sizes, int n_in,
                              void* d_out, int out_size, void* d_ws, size_t ws_size,
                              hipStream_t stream) {
    const float* x       = (const float*)d_in[0];
    const float* W_embed = (const float*)d_in[1];
    const float* L_w     = (const float*)d_in[2];
    const float* R_w     = (const float*)d_in[3];
    const float* D_w     = (const float*)d_in[4];
    const float* W_head  = (const float*)d_in[5];
    float* out = (float*)d_out;

    const int grid = BATCH / 64;   // 1024 blocks, 64 rows each
    bilinear_resnet_fused<<<grid, 256, 0, stream>>>(
        x, W_embed, L_w, R_w, D_w, W_head, out);
}

// Round 2
// 371.819 us; speedup vs baseline: 1.0463x; 1.0463x over previous
//
#include <hip/hip_runtime.h>

// BilinearResNet fused forward, round 6.
// Round 5 post-mortem: counted-vmcnt idea was right but the implementation
// lost full residency (48KB LDS -> 3 blocks/CU; grid=1024=4x256 exactly, so a
// 256-block tail ran at 1 block/CU, fully latency-exposed) and doubled the
// barrier count, plus per-iter lgkmcnt(0) drained s_load prefetch. Occupancy
// 41.6->23.9%, VALUBusy 30->19%, dur 130->183us.
// Round 6: 32-float chunks, 3 x 8KB rotating buffers = 24KB LDS -> all 1024
// blocks co-resident at 4/CU again. ONE raw s_barrier per chunk:
//   compute(c, c%3); s_waitcnt vmcnt(2) [own chunk-(c+1) loads done];
//   s_barrier [=> chunk c+1 visible to ALL + all waves done reading buf c];
//   stage(c+3, c%3) [safe overwrite].
// Chunk c+1 is issued ~2 iterations before use -> ~2000cy cover vs ~900cy HBM
// latency. No lgkmcnt(0) (ds_reads complete via data-dep before the barrier;
// keeps W_embed s_load prefetch alive). Tail x-load hoisted to kernel top
// (oldest vmem op, prologue count includes it) so its uncoalesced latency
// hides under the main loop.
// Swizzle: slot s=(it*256+wv*64+l) holds x[r=s>>3][kk=(s&7)^(r&7)]; staging
// reads a permutation within one 128B run (coalescing kept); compute reads
// buf4[lane*8 + (kk ^ (lane&7))] -> 8-lane groups cover all 32 banks,
// conflict-free (same family as round 4's measured-0-conflict layout).

#define IN_DIM   784
#define D_MODEL  16
#define HIDDEN   6
#define N_BLOCKS 4
#define N_CLS    10
#define BATCH    65536
#define NCHUNK   24        // 24 x 32-float chunks + 16-float tail

typedef const __attribute__((address_space(1))) void gvoid_t;
typedef __attribute__((address_space(3))) void svoid_t;

__global__ __launch_bounds__(256, 4) void bilinear_resnet_fused(
    const float* __restrict__ x,
    const float* __restrict__ W_embed,   // [16][784]
    const float* __restrict__ L_w,       // [4][6][16]
    const float* __restrict__ R_w,       // [4][6][16]
    const float* __restrict__ D_w,       // [4][16][6]
    const float* __restrict__ W_head,    // [10][16]
    float* __restrict__ out)
{
    __shared__ float4 buf[3][64 * 8];    // 3 x 8 KB, rotating

    const int tid  = threadIdx.x;
    const int lane = tid & 63;
    const int wv   = __builtin_amdgcn_readfirstlane(tid >> 6);  // 0..3 uniform
    const int row  = blockIdx.x * 64 + lane;
    const float* xtile = x + (size_t)blockIdx.x * 64 * IN_DIM;

    // staging decode (chunk-invariant): slot s = it*256 + wv*64 + l
    //   -> r = it*32 + wv*8 + (l>>3)   (bits: it=5, wv=4:3, l>>3=2:0)
    //   -> stored kk = (l&7) ^ (r&7) = (l&7) ^ (l>>3)   (wv*8 == 0 mod 8)
    const int sub  = lane >> 3;               // r & 7
    const int kk_l = (lane & 7) ^ sub;        // source column group (x4 floats)

    // ---- tail x columns 768..783: issue FIRST (oldest vmem op) ----
    const float4 xtail = *reinterpret_cast<const float4*>(
        x + (size_t)row * IN_DIM + 768 + wv * 4);

    float acc[D_MODEL];
#pragma unroll
    for (int d = 0; d < D_MODEL; ++d) acc[d] = 0.f;

    // issue one chunk's staging (2 x global_load_lds width=16 per thread)
    auto stage = [&](int k, int slot) {
#pragma unroll
        for (int it = 0; it < 2; ++it) {
            const int r = it * 32 + wv * 8 + sub;
            const float* g = xtile + (size_t)r * IN_DIM + k * 32 + kk_l * 4;
            char* l = (char*)(&buf[slot][0]) + (it * 256 + wv * 64) * 16;
            __builtin_amdgcn_global_load_lds((gvoid_t*)g, (svoid_t*)l, 16, 0, 0);
        }
    };

    // compute one chunk: lane = row, wave handles kk = wv*2 + {0,1}
    auto compute = [&](int c, int slot) {
        const float* wc = W_embed + c * 32 + wv * 8;   // wave-uniform -> s_load
        const float4* bsrc = buf[slot];
#pragma unroll
        for (int j = 0; j < 2; ++j) {
            const int kk = wv * 2 + j;
            const float4 xv = bsrc[lane * 8 + (kk ^ (lane & 7))];
#pragma unroll
            for (int d = 0; d < D_MODEL; ++d) {
                const float* wd = wc + d * IN_DIM + j * 4;  // uniform
                float s = acc[d];
                s = fmaf(xv.x, wd[0], s);
                s = fmaf(xv.y, wd[1], s);
                s = fmaf(xv.z, wd[2], s);
                s = fmaf(xv.w, wd[3], s);
                acc[d] = s;
            }
        }
    };

    // ---- prologue: fill 3-deep pipe. outstanding = tail(1) + 6 stage ----
    stage(0, 0);
    stage(1, 1);
    stage(2, 2);
    // wait oldest 3 = tail + chunk 0  -> 4 remain ({1,2})
    asm volatile("s_waitcnt vmcnt(4)" ::: "memory");
    __builtin_amdgcn_s_barrier();                      // chunk 0 visible to all
    asm volatile("" ::: "memory");

    // ---- steady state: c = 0..20, one barrier per chunk ----
#pragma unroll 3
    for (int c = 0; c < NCHUNK - 3; ++c) {
        compute(c, c % 3);
        // outstanding {c+1, c+2} = 4; wait chunk c+1 -> 2 remain
        asm volatile("s_waitcnt vmcnt(2)" ::: "memory");
        __builtin_amdgcn_s_barrier();  // c+1 visible to all; all done reading buf c
        asm volatile("" ::: "memory");
        stage(c + 3, c % 3);           // refill freed buffer -> {c+2, c+3} = 4
    }

    // ---- drain: c = 21, 22, 23 ----
    compute(21, 0);
    asm volatile("s_waitcnt vmcnt(2)" ::: "memory");   // chunk 22 landed
    __builtin_amdgcn_s_barrier();
    asm volatile("" ::: "memory");

    compute(22, 1);
    asm volatile("s_waitcnt vmcnt(0)" ::: "memory");   // chunk 23 landed
    __builtin_amdgcn_s_barrier();
    asm volatile("" ::: "memory");

    compute(23, 2);

    // ---- tail: columns 768..784 (xtail loaded at kernel top) ----
    {
        const float* wt = W_embed + 768 + wv * 4;   // uniform
#pragma unroll
        for (int d = 0; d < D_MODEL; ++d) {
            const float* wd = wt + d * IN_DIM;
            float s = acc[d];
            s = fmaf(xtail.x, wd[0], s);
            s = fmaf(xtail.y, wd[1], s);
            s = fmaf(xtail.z, wd[2], s);
            s = fmaf(xtail.w, wd[3], s);
            acc[d] = s;
        }
    }

    // ---- reduce 4 wave-partials per row (reuse buf[0..1], stride 17) ----
    // parts = 3*64*17 = 3264 floats < 4096 (buf[0..1]); buf[2] (chunk 23)
    // untouched; all waves finished buf[0]/buf[1] reads at the drain barriers.
    float* parts = reinterpret_cast<float*>(&buf[0][0]);
    if (wv != 0) {
#pragma unroll
        for (int d = 0; d < D_MODEL; ++d)
            parts[((wv - 1) * 64 + lane) * 17 + d] = acc[d];
    }
    __syncthreads();
    if (wv != 0) return;

#pragma unroll
    for (int d = 0; d < D_MODEL; ++d)
        acc[d] += parts[(0 * 64 + lane) * 17 + d]
                + parts[(1 * 64 + lane) * 17 + d]
                + parts[(2 * 64 + lane) * 17 + d];

    // ---- bilinear residual blocks (wave 0; uniform weights -> scalar) ----
#pragma unroll
    for (int b = 0; b < N_BLOCKS; ++b) {
        const float* Lb = L_w + b * HIDDEN * D_MODEL;
        const float* Rb = R_w + b * HIDDEN * D_MODEL;
        const float* Db = D_w + b * D_MODEL * HIDDEN;
        float h[HIDDEN];
#pragma unroll
        for (int j = 0; j < HIDDEN; ++j) {
            float u = 0.f, v = 0.f;
#pragma unroll
            for (int d = 0; d < D_MODEL; ++d) {
                u = fmaf(acc[d], Lb[j * D_MODEL + d], u);
                v = fmaf(acc[d], Rb[j * D_MODEL + d], v);
            }
            h[j] = u * v;
        }
#pragma unroll
        for (int d = 0; d < D_MODEL; ++d) {
            float s = acc[d];
#pragma unroll
            for (int j = 0; j < HIDDEN; ++j) s = fmaf(h[j], Db[d * HIDDEN + j], s);
            acc[d] = s;
        }
        float* hout = out + (size_t)N_CLS * BATCH + (size_t)b * HIDDEN * BATCH
                      + (size_t)row * HIDDEN;
#pragma unroll
        for (int j = 0; j < HIDDEN; ++j) hout[j] = h[j];
    }

    // ---- head ----
    float* lout = out + (size_t)row * N_CLS;
#pragma unroll
    for (int k = 0; k < N_CLS; ++k) {
        float s = 0.f;
#pragma unroll
        for (int d = 0; d < D_MODEL; ++d) s = fmaf(acc[d], W_head[k * D_MODEL + d], s);
        lout[k] = s;
    }
}

extern "C" void kernel_launch(void* const* d_in, const int* in_sizes, int n_in,
                              void* d_out, int out_size, void* d_ws, size_t ws_size,
                              hipStream_t stream) {
    const float* x       = (const float*)d_in[0];
    const float* W_embed = (const float*)d_in[1];
    const float* L_w     = (const float*)d_in[2];
    const float* R_w     = (const float*)d_in[3];
    const float* D_w     = (const float*)d_in[4];
    const float* W_head  = (const float*)d_in[5];
    float* out = (float*)d_out;

    const int grid = BATCH / 64;   // 1024 blocks, 64 rows each
    bilinear_resnet_fused<<<grid, 256, 0, stream>>>(
        x, W_embed, L_w, R_w, D_w, W_head, out);
}

// Round 3
// 329.549 us; speedup vs baseline: 1.1805x; 1.1283x over previous
//
#include <hip/hip_runtime.h>

// BilinearResNet fused forward, round 7.
// Round 5/6 post-mortem: counted-vmcnt grafts on the 2-barrier structure
// regressed (389/372us vs round 4's 334) -- exactly learn_hip m131-m141's
// result (T4 needs the full 8-phase regime; null/regression as a graft).
// Round 6 also re-introduced bank conflicts (8-wide XOR is NOT in the
// measured-conflict-free family; 16-consecutive-lane full-16-value XOR is).
// Round 7 = round 4's verified schedule EXACTLY (12 x 64-float chunks,
// 2 x 16KB buffers, stage->syncthreads drain, same swizzle), one change:
// 512 threads (8 waves) per block instead of 256. Wave wv covers
// kk = wv*2+{0,1} (weight ptrs stay wave-uniform -> s_loads), tail = 2
// cols/wave, reduction = 7 partial sets (30.5KB, fits buf). Occupancy:
// 4 blocks x 8 waves = 32 waves/CU = 100% (round 4: 16). The per-chunk
// vmcnt(0) drain stalls are filled by 24 other waves instead of 12.
// __launch_bounds__(512,8) caps VGPR at 64 (round 4 measured 44 with MORE
// per-thread work, so no spill expected; WRITE_SIZE inflation = spill alarm).

#define IN_DIM   784
#define D_MODEL  16
#define HIDDEN   6
#define N_BLOCKS 4
#define N_CLS    10
#define BATCH    65536
#define NCHUNK   12        // 12 x 64-float chunks + 16-float tail

typedef const __attribute__((address_space(1))) void gvoid_t;
typedef __attribute__((address_space(3))) void svoid_t;

__global__ __launch_bounds__(512, 8) void bilinear_resnet_fused(
    const float* __restrict__ x,
    const float* __restrict__ W_embed,   // [16][784]
    const float* __restrict__ L_w,       // [4][6][16]
    const float* __restrict__ R_w,       // [4][6][16]
    const float* __restrict__ D_w,       // [4][16][6]
    const float* __restrict__ W_head,    // [10][16]
    float* __restrict__ out)
{
    __shared__ float4 buf[2][64 * 16];   // 2 x 16 KB

    const int tid  = threadIdx.x;
    const int lane = tid & 63;
    const int wv   = __builtin_amdgcn_readfirstlane(tid >> 6);  // 0..7 uniform
    const int row  = blockIdx.x * 64 + lane;
    const float* xtile = x + (size_t)blockIdx.x * 64 * IN_DIM;

    // staging decode (chunk-invariant): slot = it*512 + tid
    //   -> r = it*32 + (tid>>4), g = tid&15, stored content = x[r][g ^ (r&15)]
    //   r&15 = (tid>>4)&15 (32 = 0 mod 16, so it-independent)
    const int rhalf = tid >> 4;                  // r - it*32, 0..31
    const int kk_l  = (tid & 15) ^ (rhalf & 15); // source column group (x4 floats)

    // tail x columns: wave wv covers cols 768 + wv*2 + {0,1} (hoisted load)
    const float2 xtail = *reinterpret_cast<const float2*>(
        x + (size_t)row * IN_DIM + 768 + wv * 2);

    float acc[D_MODEL];
#pragma unroll
    for (int d = 0; d < D_MODEL; ++d) acc[d] = 0.f;

    // issue one chunk's staging (2 x global_load_lds width=16 per thread)
    auto stage = [&](int k, int b) {
#pragma unroll
        for (int it = 0; it < 2; ++it) {
            const int r = it * 32 + rhalf;
            const float* g = xtile + (size_t)r * IN_DIM + k * 64 + kk_l * 4;
            char* l = (char*)(&buf[b][0]) + (it * 512 + tid) * 16;
            __builtin_amdgcn_global_load_lds((gvoid_t*)g, (svoid_t*)l, 16, 0, 0);
        }
    };

    // compute one chunk: lane = row, wave handles kk = wv*2 + {0,1}
    auto compute = [&](int c, int b) {
        const float* wc = W_embed + c * 64 + wv * 8;   // wave-uniform -> s_load
        const float4* bsrc = buf[b];
#pragma unroll
        for (int j = 0; j < 2; ++j) {
            const int kk = wv * 2 + j;
            const float4 xv = bsrc[lane * 16 + (kk ^ (lane & 15))];
#pragma unroll
            for (int d = 0; d < D_MODEL; ++d) {
                const float* wd = wc + d * IN_DIM + j * 4;  // uniform
                float s = acc[d];
                s = fmaf(xv.x, wd[0], s);
                s = fmaf(xv.y, wd[1], s);
                s = fmaf(xv.z, wd[2], s);
                s = fmaf(xv.w, wd[3], s);
                acc[d] = s;
            }
        }
    };

    // ---- round-4 schedule: stage -> sync; {stage next; compute; sync} ----
    stage(0, 0);
    __syncthreads();

    for (int c = 0; c < NCHUNK; ++c) {
        if (c + 1 < NCHUNK) stage(c + 1, (c + 1) & 1);
        compute(c, c & 1);
        __syncthreads();   // drains vmcnt (prefetch done) + barrier
    }

    // ---- tail: wave wv covers cols 768 + wv*2 + {0,1} ----
    {
        const float* wt = W_embed + 768 + wv * 2;   // uniform
#pragma unroll
        for (int d = 0; d < D_MODEL; ++d) {
            const float* wd = wt + d * IN_DIM;
            acc[d] = fmaf(xtail.x, wd[0], fmaf(xtail.y, wd[1], acc[d]));
        }
    }

    // ---- reduce 8 wave-partials per row (reuse buf, stride 17) ----
    // 7 * 64 * 17 = 7616 floats = 30464 B <= 32 KB; all waves passed the
    // final __syncthreads (done reading buf), writes then re-synced below.
    float* parts = reinterpret_cast<float*>(&buf[0][0]);
    if (wv != 0) {
#pragma unroll
        for (int d = 0; d < D_MODEL; ++d)
            parts[((wv - 1) * 64 + lane) * 17 + d] = acc[d];
    }
    __syncthreads();
    if (wv != 0) return;

#pragma unroll
    for (int p = 0; p < 7; ++p)
#pragma unroll
        for (int d = 0; d < D_MODEL; ++d)
            acc[d] += parts[(p * 64 + lane) * 17 + d];

    // ---- bilinear residual blocks (wave 0; uniform weights -> scalar) ----
#pragma unroll
    for (int b = 0; b < N_BLOCKS; ++b) {
        const float* Lb = L_w + b * HIDDEN * D_MODEL;
        const float* Rb = R_w + b * HIDDEN * D_MODEL;
        const float* Db = D_w + b * D_MODEL * HIDDEN;
        float h[HIDDEN];
#pragma unroll
        for (int j = 0; j < HIDDEN; ++j) {
            float u = 0.f, v = 0.f;
#pragma unroll
            for (int d = 0; d < D_MODEL; ++d) {
                u = fmaf(acc[d], Lb[j * D_MODEL + d], u);
                v = fmaf(acc[d], Rb[j * D_MODEL + d], v);
            }
            h[j] = u * v;
        }
#pragma unroll
        for (int d = 0; d < D_MODEL; ++d) {
            float s = acc[d];
#pragma unroll
            for (int j = 0; j < HIDDEN; ++j) s = fmaf(h[j], Db[d * HIDDEN + j], s);
            acc[d] = s;
        }
        float* hout = out + (size_t)N_CLS * BATCH + (size_t)b * HIDDEN * BATCH
                      + (size_t)row * HIDDEN;
#pragma unroll
        for (int j = 0; j < HIDDEN; ++j) hout[j] = h[j];
    }

    // ---- head ----
    float* lout = out + (size_t)row * N_CLS;
#pragma unroll
    for (int k = 0; k < N_CLS; ++k) {
        float s = 0.f;
#pragma unroll
        for (int d = 0; d < D_MODEL; ++d) s = fmaf(acc[d], W_head[k * D_MODEL + d], s);
        lout[k] = s;
    }
}

extern "C" void kernel_launch(void* const* d_in, const int* in_sizes, int n_in,
                              void* d_out, int out_size, void* d_ws, size_t ws_size,
                              hipStream_t stream) {
    const float* x       = (const float*)d_in[0];
    const float* W_embed = (const float*)d_in[1];
    const float* L_w     = (const float*)d_in[2];
    const float* R_w     = (const float*)d_in[3];
    const float* D_w     = (const float*)d_in[4];
    const float* W_head  = (const float*)d_in[5];
    float* out = (float*)d_out;

    const int grid = BATCH / 64;   // 1024 blocks, 64 rows each, 8 waves
    bilinear_resnet_fused<<<grid, 512, 0, stream>>>(
        x, W_embed, L_w, R_w, D_w, W_head, out);
}

// Round 4
// 323.345 us; speedup vs baseline: 1.2032x; 1.0192x over previous
//
#include <hip/hip_runtime.h>

// BilinearResNet fused forward, round 8.
// Round 7 post-mortem: 2x TLP (16->32 waves/CU, occ 72.7%) changed NOTHING
// (130->137us), VALUBusy halved to 10%. Across rounds 4/6/7 every schedule
// keeping global_load_lds sits at ~1.5 TB/s effective staging (5.6 GB/s/CU).
// Theory that fits all data: the per-CU LDS-DMA path has a small fixed
// outstanding capacity (~4KB); throughput = cap/latency. L2-resident staging
// (m97 GEMM): 200cy -> ~50 GB/s/CU (matches its 55). L3/HBM streaming (us):
// ~2000cy -> ~5 GB/s/CU (matches our 5.6). No occupancy/vmcnt scheme can fix
// a per-CU queue. Fix: stage via PLAIN vector loads to named VGPRs (the 6.3
// TB/s copy ubench path; per-CU in-flight capacity is ample), then
// ds_write_b128 into the IDENTICAL verified LDS layout. Prior session's
// reg-staging failure was a rule-#20 scratch demotion (runtime-indexed
// pf[4]); pf0/pf1 here are named scalars.
// Schedule (T14 split, one __syncthreads per chunk):
//   iter c: compute(c, buf[c&1]);
//           ds_write pf -> buf[(c+1)&1]   (compiler-inserted vmcnt wait;
//                                          loads were issued a full compute
//                                          phase ago -> already landed)
//           __syncthreads();              (lgkm drain -> writes visible)
//           load chunk c+2 -> pf0/pf1     (AFTER barrier: next drain finds
//                                          them covered by compute(c+1))
// Everything else byte-identical to round 7 (512 thr, 8 waves, 2x16KB buf,
// XOR swizzle measured 0-conflict, wave-uniform W s_loads, same epilogue).

#define IN_DIM   784
#define D_MODEL  16
#define HIDDEN   6
#define N_BLOCKS 4
#define N_CLS    10
#define BATCH    65536
#define NCHUNK   12        // 12 x 64-float chunks + 16-float tail

__global__ __launch_bounds__(512, 8) void bilinear_resnet_fused(
    const float* __restrict__ x,
    const float* __restrict__ W_embed,   // [16][784]
    const float* __restrict__ L_w,       // [4][6][16]
    const float* __restrict__ R_w,       // [4][6][16]
    const float* __restrict__ D_w,       // [4][16][6]
    const float* __restrict__ W_head,    // [10][16]
    float* __restrict__ out)
{
    __shared__ float4 buf[2][64 * 16];   // 2 x 16 KB

    const int tid  = threadIdx.x;
    const int lane = tid & 63;
    const int wv   = __builtin_amdgcn_readfirstlane(tid >> 6);  // 0..7 uniform
    const int row  = blockIdx.x * 64 + lane;
    const float* xtile = x + (size_t)blockIdx.x * 64 * IN_DIM;

    // staging decode (chunk-invariant): slot = it*512 + tid
    //   -> r = it*32 + (tid>>4), stored content = x[r][(tid&15) ^ (r&15)]
    const int rhalf = tid >> 4;                  // r - it*32, 0..31
    const int kk_l  = (tid & 15) ^ (rhalf & 15); // source column group (x4)

    // tail x columns: wave wv covers cols 768 + wv*2 + {0,1} (hoisted load)
    const float2 xtail = *reinterpret_cast<const float2*>(
        x + (size_t)row * IN_DIM + 768 + wv * 2);

    float acc[D_MODEL];
#pragma unroll
    for (int d = 0; d < D_MODEL; ++d) acc[d] = 0.f;

    // named prefetch registers (rule #20: never a runtime-indexed array)
    float4 pf0, pf1;

    auto stage_load = [&](int k) {
        const float* g0 = xtile + (size_t)(rhalf) * IN_DIM + k * 64 + kk_l * 4;
        const float* g1 = xtile + (size_t)(32 + rhalf) * IN_DIM + k * 64 + kk_l * 4;
        pf0 = *reinterpret_cast<const float4*>(g0);
        pf1 = *reinterpret_cast<const float4*>(g1);
    };
    auto stage_write = [&](int b) {
        buf[b][0 * 512 + tid] = pf0;   // ds_write_b128, uniform 8/bank
        buf[b][1 * 512 + tid] = pf1;
    };

    // compute one chunk: lane = row, wave handles kk = wv*2 + {0,1}
    auto compute = [&](int c, int b) {
        const float* wc = W_embed + c * 64 + wv * 8;   // wave-uniform -> s_load
        const float4* bsrc = buf[b];
#pragma unroll
        for (int j = 0; j < 2; ++j) {
            const int kk = wv * 2 + j;
            const float4 xv = bsrc[lane * 16 + (kk ^ (lane & 15))];
#pragma unroll
            for (int d = 0; d < D_MODEL; ++d) {
                const float* wd = wc + d * IN_DIM + j * 4;  // uniform
                float s = acc[d];
                s = fmaf(xv.x, wd[0], s);
                s = fmaf(xv.y, wd[1], s);
                s = fmaf(xv.z, wd[2], s);
                s = fmaf(xv.w, wd[3], s);
                acc[d] = s;
            }
        }
    };

    // ---- prologue ----
    stage_load(0);
    stage_write(0);          // compiler waits vmcnt for pf use
    __syncthreads();
    stage_load(1);           // issued after barrier; lands under compute(0)

    // ---- main loop: one barrier per chunk ----
    for (int c = 0; c < NCHUNK; ++c) {
        compute(c, c & 1);
        if (c + 1 < NCHUNK) {
            stage_write((c + 1) & 1);        // other buffer than compute read
            __syncthreads();                 // writes visible to all
            if (c + 2 < NCHUNK) stage_load(c + 2);
        }
    }
    __syncthreads();   // all waves done reading buf before parts reuse

    // ---- tail: wave wv covers cols 768 + wv*2 + {0,1} ----
    {
        const float* wt = W_embed + 768 + wv * 2;   // uniform
#pragma unroll
        for (int d = 0; d < D_MODEL; ++d) {
            const float* wd = wt + d * IN_DIM;
            acc[d] = fmaf(xtail.x, wd[0], fmaf(xtail.y, wd[1], acc[d]));
        }
    }

    // ---- reduce 8 wave-partials per row (reuse buf, stride 17) ----
    float* parts = reinterpret_cast<float*>(&buf[0][0]);
    if (wv != 0) {
#pragma unroll
        for (int d = 0; d < D_MODEL; ++d)
            parts[((wv - 1) * 64 + lane) * 17 + d] = acc[d];
    }
    __syncthreads();
    if (wv != 0) return;

#pragma unroll
    for (int p = 0; p < 7; ++p)
#pragma unroll
        for (int d = 0; d < D_MODEL; ++d)
            acc[d] += parts[(p * 64 + lane) * 17 + d];

    // ---- bilinear residual blocks (wave 0; uniform weights -> scalar) ----
#pragma unroll
    for (int b = 0; b < N_BLOCKS; ++b) {
        const float* Lb = L_w + b * HIDDEN * D_MODEL;
        const float* Rb = R_w + b * HIDDEN * D_MODEL;
        const float* Db = D_w + b * D_MODEL * HIDDEN;
        float h[HIDDEN];
#pragma unroll
        for (int j = 0; j < HIDDEN; ++j) {
            float u = 0.f, v = 0.f;
#pragma unroll
            for (int d = 0; d < D_MODEL; ++d) {
                u = fmaf(acc[d], Lb[j * D_MODEL + d], u);
                v = fmaf(acc[d], Rb[j * D_MODEL + d], v);
            }
            h[j] = u * v;
        }
#pragma unroll
        for (int d = 0; d < D_MODEL; ++d) {
            float s = acc[d];
#pragma unroll
            for (int j = 0; j < HIDDEN; ++j) s = fmaf(h[j], Db[d * HIDDEN + j], s);
            acc[d] = s;
        }
        float* hout = out + (size_t)N_CLS * BATCH + (size_t)b * HIDDEN * BATCH
                      + (size_t)row * HIDDEN;
#pragma unroll
        for (int j = 0; j < HIDDEN; ++j) hout[j] = h[j];
    }

    // ---- head ----
    float* lout = out + (size_t)row * N_CLS;
#pragma unroll
    for (int k = 0; k < N_CLS; ++k) {
        float s = 0.f;
#pragma unroll
        for (int d = 0; d < D_MODEL; ++d) s = fmaf(acc[d], W_head[k * D_MODEL + d], s);
        lout[k] = s;
    }
}

extern "C" void kernel_launch(void* const* d_in, const int* in_sizes, int n_in,
                              void* d_out, int out_size, void* d_ws, size_t ws_size,
                              hipStream_t stream) {
    const float* x       = (const float*)d_in[0];
    const float* W_embed = (const float*)d_in[1];
    const float* L_w     = (const float*)d_in[2];
    const float* R_w     = (const float*)d_in[3];
    const float* D_w     = (const float*)d_in[4];
    const float* W_head  = (const float*)d_in[5];
    float* out = (float*)d_out;

    const int grid = BATCH / 64;   // 1024 blocks, 64 rows each, 8 waves
    bilinear_resnet_fused<<<grid, 512, 0, stream>>>(
        x, W_embed, L_w, R_w, D_w, W_head, out);
}